// Round 1
// baseline (607.156 us; speedup 1.0000x reference)
//
#include <hip/hip_runtime.h>
#include <stdint.h>

typedef __attribute__((ext_vector_type(8))) short  short8;   // 8 bf16 = 4 VGPR MFMA frag
typedef __attribute__((ext_vector_type(4))) float  f32x4;    // MFMA accumulator
typedef __attribute__((ext_vector_type(4))) unsigned short us4;

static __device__ __forceinline__ unsigned short f2bf(float x) {
  unsigned u = __builtin_bit_cast(unsigned, x);
  u += 0x7FFFu + ((u >> 16) & 1u);          // round-to-nearest-even
  return (unsigned short)(u >> 16);
}

// ---------------------------------------------------------------- fp32 -> bf16
__global__ __launch_bounds__(256) void cvt_kernel(const float* __restrict__ in,
                                                  unsigned short* __restrict__ out,
                                                  int n4) {
  int i = blockIdx.x * blockDim.x + threadIdx.x;
  int stride = gridDim.x * blockDim.x;
  for (; i < n4; i += stride) {
    f32x4 v = *((const f32x4*)in + i);
    us4 o = { f2bf(v[0]), f2bf(v[1]), f2bf(v[2]), f2bf(v[3]) };
    *((us4*)out + i) = o;
  }
}

// ------------------------------------------------------- async global->LDS 16B
static __device__ __forceinline__ void g2l16(const void* g, void* l) {
  __builtin_amdgcn_global_load_lds(
      (const __attribute__((address_space(1))) void*)g,
      (__attribute__((address_space(3))) void*)l, 16, 0, 0);
}

// ---------------------------------------------------------------- NT GEMM
// C[m][n] = sum_k A[m][k] * W[n][k].  A: MxK bf16, W: NxK bf16.
// BM=BN=128, BK=32, 256 threads = 4 waves (2x2), 64x64 per wave.
// MODE 0: bf16 out, row-major MxN.
// MODE 1: bf16 out transposed for V: out[(b*1024+n)*2048 + s], m = b*2048+s.
// MODE 2: f32 out, row-major MxN (final output).
template <int MODE>
__global__ __launch_bounds__(256) void gemm_nt(const unsigned short* __restrict__ A,
                                               const unsigned short* __restrict__ W,
                                               void* __restrict__ outp,
                                               int M, int N, int K) {
  __shared__ unsigned short Alds[128 * 32];
  __shared__ unsigned short Blds[128 * 32];
  const int tid  = threadIdx.x;
  const int lane = tid & 63;
  const int w    = tid >> 6;
  const int g    = lane >> 4;
  const int li   = lane & 15;
  const int m0 = blockIdx.y * 128;
  const int n0 = blockIdx.x * 128;
  const int wm = (w >> 1) * 64;
  const int wn = (w & 1) * 64;

  // LDS read offsets (ushort units). Row stride 32 bf16; 16B chunk swizzled by
  // (row>>1)&3 so a b128 frag read is 2-way (free) instead of 8-way.
  int aoff[4], boff[4];
#pragma unroll
  for (int mi = 0; mi < 4; ++mi) {
    int row = wm + mi * 16 + li;
    aoff[mi] = row * 32 + (g ^ ((row >> 1) & 3)) * 8;
  }
#pragma unroll
  for (int ni = 0; ni < 4; ++ni) {
    int col = wn + ni * 16 + li;
    boff[ni] = col * 32 + (g ^ ((col >> 1) & 3)) * 8;
  }

  // Staging: 512 16B slots per tile; thread handles slots tid and tid+256.
  // slot -> (row = s>>2, lds chunk c = s&3) holds global chunk c ^ ((row>>1)&3).
  const int s1 = tid, s2 = 256 + tid;
  const int r1 = s1 >> 2, gc1 = (s1 & 3) ^ ((r1 >> 1) & 3);
  const int r2 = s2 >> 2, gc2 = (s2 & 3) ^ ((r2 >> 1) & 3);
  const unsigned short* gA1 = A + (size_t)(m0 + r1) * K + gc1 * 8;
  const unsigned short* gA2 = A + (size_t)(m0 + r2) * K + gc2 * 8;
  const unsigned short* gB1 = W + (size_t)(n0 + r1) * K + gc1 * 8;
  const unsigned short* gB2 = W + (size_t)(n0 + r2) * K + gc2 * 8;
  unsigned short* lA1 = &Alds[w * 512];
  unsigned short* lA2 = &Alds[2048 + w * 512];
  unsigned short* lB1 = &Blds[w * 512];
  unsigned short* lB2 = &Blds[2048 + w * 512];

  f32x4 acc[4][4] = {};

  const int nkt = K >> 5;
#pragma unroll 1
  for (int kt = 0; kt < nkt; ++kt) {
    g2l16(gA1, lA1); g2l16(gA2, lA2);
    g2l16(gB1, lB1); g2l16(gB2, lB2);
    gA1 += 32; gA2 += 32; gB1 += 32; gB2 += 32;
    asm volatile("s_waitcnt vmcnt(0)" ::: "memory");
    __syncthreads();
    short8 af[4], bf[4];
#pragma unroll
    for (int mi = 0; mi < 4; ++mi) af[mi] = *(const short8*)&Alds[aoff[mi]];
#pragma unroll
    for (int ni = 0; ni < 4; ++ni) bf[ni] = *(const short8*)&Blds[boff[ni]];
#pragma unroll
    for (int mi = 0; mi < 4; ++mi)
#pragma unroll
      for (int ni = 0; ni < 4; ++ni)
        acc[mi][ni] = __builtin_amdgcn_mfma_f32_16x16x32_bf16(af[mi], bf[ni], acc[mi][ni], 0, 0, 0);
    __syncthreads();
  }

  if (MODE == 0) {
    unsigned short* C = (unsigned short*)outp;
#pragma unroll
    for (int mi = 0; mi < 4; ++mi) {
      int mb = m0 + wm + mi * 16 + g * 4;
#pragma unroll
      for (int ni = 0; ni < 4; ++ni) {
        int n = n0 + wn + ni * 16 + li;
#pragma unroll
        for (int r = 0; r < 4; ++r)
          C[(size_t)(mb + r) * N + n] = f2bf(acc[mi][ni][r]);
      }
    }
  } else if (MODE == 1) {
    unsigned short* C = (unsigned short*)outp;   // (B*1024) x 2048
#pragma unroll
    for (int mi = 0; mi < 4; ++mi) {
      int mb = m0 + wm + mi * 16 + g * 4;
      int bb = mb >> 11, s = mb & 2047;
#pragma unroll
      for (int ni = 0; ni < 4; ++ni) {
        int n = n0 + wn + ni * 16 + li;
        us4 pk = { f2bf(acc[mi][ni][0]), f2bf(acc[mi][ni][1]),
                   f2bf(acc[mi][ni][2]), f2bf(acc[mi][ni][3]) };
        *(us4*)&C[(size_t)(bb * 1024 + n) * 2048 + s] = pk;
      }
    }
  } else {
    float* C = (float*)outp;
#pragma unroll
    for (int mi = 0; mi < 4; ++mi) {
      int mb = m0 + wm + mi * 16 + g * 4;
#pragma unroll
      for (int ni = 0; ni < 4; ++ni) {
        int n = n0 + wn + ni * 16 + li;
#pragma unroll
        for (int r = 0; r < 4; ++r)
          C[(size_t)(mb + r) * N + n] = acc[mi][ni][r];
      }
    }
  }
}

// ---------------------------------------------------------------- attention
// One wave = 64 q rows of one (b,h). 4 independent waves per block.
// Q in registers; K,Vt fragments read straight from global (L2-resident);
// P goes through a per-wave LDS round-trip (stride 72 -> conflict-free b128).
// Online softmax in log2 domain; row-sum via extra ones-column MFMA.
__global__ __launch_bounds__(256) void attn_kernel(const unsigned short* __restrict__ Qp,
                                                   const unsigned short* __restrict__ Kp,
                                                   const unsigned short* __restrict__ Vt,
                                                   const int* __restrict__ pmask,
                                                   unsigned short* __restrict__ att) {
  __shared__ unsigned short Plds[4][64 * 72];
  const int tid = threadIdx.x, lane = tid & 63, w = tid >> 6;
  const int g = lane >> 4, li = lane & 15;
  const int bh = blockIdx.y, b = bh >> 4, h = bh & 15;
  const int qw = (blockIdx.x * 4 + w) * 64;

  short8 qfr[4][2];
#pragma unroll
  for (int mi = 0; mi < 4; ++mi)
#pragma unroll
    for (int ks = 0; ks < 2; ++ks)
      qfr[mi][ks] = *(const short8*)&Qp[((size_t)(b * 2048 + qw + mi * 16 + li)) * 1024 +
                                        h * 64 + ks * 32 + g * 8];

  f32x4 acco[4][4] = {};
  f32x4 lacc[4] = {};
  float mrow[4][4];
#pragma unroll
  for (int mi = 0; mi < 4; ++mi)
#pragma unroll
    for (int r = 0; r < 4; ++r) mrow[mi][r] = -3.0e38f;

  short8 ones;
#pragma unroll
  for (int j = 0; j < 8; ++j) ones[j] = (short)0x3F80;  // bf16 1.0

  unsigned short* Pl = &Plds[w][0];
  const float sc = 0.125f * 1.44269504088896340736f;    // scale * log2(e)

  const int nkt = (qw >> 6) + 1;                        // causal tile skip
#pragma unroll 1
  for (int kt = 0; kt < nkt; ++kt) {
    // ---- QK^T
    f32x4 s[4][4] = {};
#pragma unroll
    for (int ks = 0; ks < 2; ++ks) {
      short8 kf[4];
#pragma unroll
      for (int ni = 0; ni < 4; ++ni)
        kf[ni] = *(const short8*)&Kp[((size_t)(b * 2048 + kt * 64 + ni * 16 + li)) * 1024 +
                                     h * 64 + ks * 32 + g * 8];
#pragma unroll
      for (int mi = 0; mi < 4; ++mi)
#pragma unroll
        for (int ni = 0; ni < 4; ++ni)
          s[mi][ni] = __builtin_amdgcn_mfma_f32_16x16x32_bf16(qfr[mi][ks], kf[ni], s[mi][ni], 0, 0, 0);
    }
    // ---- scale + masks (log2 domain)
    int pm[4];
#pragma unroll
    for (int ni = 0; ni < 4; ++ni) pm[ni] = pmask[b * 2048 + kt * 64 + ni * 16 + li];
#pragma unroll
    for (int mi = 0; mi < 4; ++mi) {
      int qb0 = qw + mi * 16 + g * 4;
#pragma unroll
      for (int ni = 0; ni < 4; ++ni) {
        int key = kt * 64 + ni * 16 + li;
        bool pz = (pm[ni] == 0);
#pragma unroll
        for (int r = 0; r < 4; ++r) {
          float v = s[mi][ni][r] * sc;
          if (pz || key > qb0 + r) v = -1.0e9f;
          s[mi][ni][r] = v;
        }
      }
    }
    // ---- row max (over 16 lanes = 16 key columns), rescale O and l
#pragma unroll
    for (int mi = 0; mi < 4; ++mi) {
      f32x4 t = s[mi][0];
#pragma unroll
      for (int ni = 1; ni < 4; ++ni)
#pragma unroll
        for (int r = 0; r < 4; ++r) t[r] = fmaxf(t[r], s[mi][ni][r]);
#pragma unroll
      for (int r = 0; r < 4; ++r) {
        float v = t[r];
        v = fmaxf(v, __shfl_xor(v, 1));
        v = fmaxf(v, __shfl_xor(v, 2));
        v = fmaxf(v, __shfl_xor(v, 4));
        v = fmaxf(v, __shfl_xor(v, 8));
        float mn = fmaxf(mrow[mi][r], v);
        float al = exp2f(mrow[mi][r] - mn);
        mrow[mi][r] = mn;
        lacc[mi][r] *= al;
#pragma unroll
        for (int df = 0; df < 4; ++df) acco[mi][df][r] *= al;
      }
    }
    // ---- p = exp2(s - m), bf16, to LDS (row-major, stride 72)
#pragma unroll
    for (int mi = 0; mi < 4; ++mi)
#pragma unroll
      for (int ni = 0; ni < 4; ++ni)
#pragma unroll
        for (int r = 0; r < 4; ++r) {
          float p = exp2f(s[mi][ni][r] - mrow[mi][r]);
          Pl[(mi * 16 + g * 4 + r) * 72 + ni * 16 + li] = f2bf(p);
        }
    // ---- PV (+ ones column for row-sum l)
#pragma unroll
    for (int ks = 0; ks < 2; ++ks) {
      short8 vf[4];
#pragma unroll
      for (int df = 0; df < 4; ++df)
        vf[df] = *(const short8*)&Vt[((size_t)(b * 1024 + h * 64 + df * 16 + li)) * 2048 +
                                     kt * 64 + ks * 32 + g * 8];
#pragma unroll
      for (int mi = 0; mi < 4; ++mi) {
        short8 pa = *(const short8*)&Pl[(mi * 16 + li) * 72 + ks * 32 + g * 8];
#pragma unroll
        for (int df = 0; df < 4; ++df)
          acco[mi][df] = __builtin_amdgcn_mfma_f32_16x16x32_bf16(pa, vf[df], acco[mi][df], 0, 0, 0);
        lacc[mi] = __builtin_amdgcn_mfma_f32_16x16x32_bf16(pa, ones, lacc[mi], 0, 0, 0);
      }
    }
  }
  // ---- epilogue: O / l -> bf16 att (B,S,D)
#pragma unroll
  for (int mi = 0; mi < 4; ++mi) {
    int qb0 = qw + mi * 16 + g * 4;
#pragma unroll
    for (int df = 0; df < 4; ++df) {
      int d = h * 64 + df * 16 + li;
#pragma unroll
      for (int r = 0; r < 4; ++r) {
        float o = acco[mi][df][r] / lacc[mi][r];
        att[(size_t)(b * 2048 + qb0 + r) * 1024 + d] = f2bf(o);
      }
    }
  }
}

// ---------------------------------------------------------------- launch
extern "C" void kernel_launch(void* const* d_in, const int* in_sizes, int n_in,
                              void* d_out, int out_size, void* d_ws, size_t ws_size,
                              hipStream_t stream) {
  const float* q_raw  = (const float*)d_in[0];
  const float* kv_raw = (const float*)d_in[1];
  const int*   pmask  = (const int*)d_in[2];
  const float* Wq = (const float*)d_in[3];
  const float* Wk = (const float*)d_in[4];
  const float* Wv = (const float*)d_in[5];
  const float* Wo = (const float*)d_in[6];
  float* out = (float*)d_out;

  const size_t NEL = 8388608;   // B*S*D
  const size_t WEL = 1048576;   // D*D
  unsigned short* ws   = (unsigned short*)d_ws;
  unsigned short* qbf  = ws;              // reused as att after projections
  unsigned short* kvbf = qbf + NEL;
  unsigned short* wbf  = kvbf + NEL;      // Wq,Wk,Wv,Wo bf16 back-to-back
  unsigned short* Qp   = wbf + 4 * WEL;
  unsigned short* Kp   = Qp + NEL;
  unsigned short* Vtp  = Kp + NEL;        // (B,H,DH,S) transposed V
  unsigned short* att  = qbf;             // alias (qbf dead after projections)

  cvt_kernel<<<2048, 256, 0, stream>>>(q_raw,  qbf,  (int)(NEL / 4));
  cvt_kernel<<<2048, 256, 0, stream>>>(kv_raw, kvbf, (int)(NEL / 4));
  cvt_kernel<<<256, 256, 0, stream>>>(Wq, wbf,           (int)(WEL / 4));
  cvt_kernel<<<256, 256, 0, stream>>>(Wk, wbf + WEL,     (int)(WEL / 4));
  cvt_kernel<<<256, 256, 0, stream>>>(Wv, wbf + 2 * WEL, (int)(WEL / 4));
  cvt_kernel<<<256, 256, 0, stream>>>(Wo, wbf + 3 * WEL, (int)(WEL / 4));

  dim3 gg(8, 64);  // N/128, M/128
  gemm_nt<0><<<gg, 256, 0, stream>>>(qbf,  wbf,           (void*)Qp,  8192, 1024, 1024);
  gemm_nt<0><<<gg, 256, 0, stream>>>(kvbf, wbf + WEL,     (void*)Kp,  8192, 1024, 1024);
  gemm_nt<1><<<gg, 256, 0, stream>>>(kvbf, wbf + 2 * WEL, (void*)Vtp, 8192, 1024, 1024);

  attn_kernel<<<dim3(8, 64), 256, 0, stream>>>(Qp, Kp, Vtp, pmask, att);

  gemm_nt<2><<<gg, 256, 0, stream>>>(att, wbf + 3 * WEL, (void*)out, 8192, 1024, 1024);
}

// Round 2
// 266.676 us; speedup vs baseline: 2.2768x; 2.2768x over previous
//
#include <hip/hip_runtime.h>
#include <stdint.h>

typedef __attribute__((ext_vector_type(8))) short  short8;   // 8 bf16 = 4 VGPR MFMA frag
typedef __attribute__((ext_vector_type(4))) float  f32x4;    // MFMA accumulator
typedef __attribute__((ext_vector_type(4))) unsigned short us4;

static __device__ __forceinline__ unsigned short f2bf(float x) {
  unsigned u = __builtin_bit_cast(unsigned, x);
  u += 0x7FFFu + ((u >> 16) & 1u);          // round-to-nearest-even
  return (unsigned short)(u >> 16);
}

// ---------------------------------------------------------------- fp32 -> bf16
__global__ __launch_bounds__(256) void cvt_kernel(const float* __restrict__ in,
                                                  unsigned short* __restrict__ out,
                                                  int n4) {
  int i = blockIdx.x * blockDim.x + threadIdx.x;
  int stride = gridDim.x * blockDim.x;
  for (; i < n4; i += stride) {
    f32x4 v = *((const f32x4*)in + i);
    us4 o = { f2bf(v[0]), f2bf(v[1]), f2bf(v[2]), f2bf(v[3]) };
    *((us4*)out + i) = o;
  }
}

// ---------------------------------------------------------------- pmask -> f32 bias
__global__ __launch_bounds__(256) void bias_kernel(const int* __restrict__ pm,
                                                   float* __restrict__ bias, int n) {
  int i = blockIdx.x * blockDim.x + threadIdx.x;
  if (i < n) bias[i] = (pm[i] == 0) ? -1.0e9f : 0.0f;
}

// ------------------------------------------------------- async global->LDS 16B
static __device__ __forceinline__ void g2l16(const void* g, void* l) {
  __builtin_amdgcn_global_load_lds(
      (const __attribute__((address_space(1))) void*)g,
      (__attribute__((address_space(3))) void*)l, 16, 0, 0);
}

// ---------------------------------------------------------------- NT GEMM
// C[m][n] = sum_k A[m][k] * W[n][k].  A: MxK bf16, W: NxK bf16.
// BM=BN=128, BK=32, 256 threads = 4 waves (2x2), 64x64 per wave.
template <int MODE>
__global__ __launch_bounds__(256) void gemm_nt(const unsigned short* __restrict__ A,
                                               const unsigned short* __restrict__ W,
                                               void* __restrict__ outp,
                                               int M, int N, int K) {
  __shared__ unsigned short Alds[128 * 32];
  __shared__ unsigned short Blds[128 * 32];
  const int tid  = threadIdx.x;
  const int lane = tid & 63;
  const int w    = tid >> 6;
  const int g    = lane >> 4;
  const int li   = lane & 15;
  const int m0 = blockIdx.y * 128;
  const int n0 = blockIdx.x * 128;
  const int wm = (w >> 1) * 64;
  const int wn = (w & 1) * 64;

  int aoff[4], boff[4];
#pragma unroll
  for (int mi = 0; mi < 4; ++mi) {
    int row = wm + mi * 16 + li;
    aoff[mi] = row * 32 + (g ^ ((row >> 1) & 3)) * 8;
  }
#pragma unroll
  for (int ni = 0; ni < 4; ++ni) {
    int col = wn + ni * 16 + li;
    boff[ni] = col * 32 + (g ^ ((col >> 1) & 3)) * 8;
  }

  const int s1 = tid, s2 = 256 + tid;
  const int r1 = s1 >> 2, gc1 = (s1 & 3) ^ ((r1 >> 1) & 3);
  const int r2 = s2 >> 2, gc2 = (s2 & 3) ^ ((r2 >> 1) & 3);
  const unsigned short* gA1 = A + (size_t)(m0 + r1) * K + gc1 * 8;
  const unsigned short* gA2 = A + (size_t)(m0 + r2) * K + gc2 * 8;
  const unsigned short* gB1 = W + (size_t)(n0 + r1) * K + gc1 * 8;
  const unsigned short* gB2 = W + (size_t)(n0 + r2) * K + gc2 * 8;
  unsigned short* lA1 = &Alds[w * 512];
  unsigned short* lA2 = &Alds[2048 + w * 512];
  unsigned short* lB1 = &Blds[w * 512];
  unsigned short* lB2 = &Blds[2048 + w * 512];

  f32x4 acc[4][4] = {};

  const int nkt = K >> 5;
#pragma unroll 1
  for (int kt = 0; kt < nkt; ++kt) {
    g2l16(gA1, lA1); g2l16(gA2, lA2);
    g2l16(gB1, lB1); g2l16(gB2, lB2);
    gA1 += 32; gA2 += 32; gB1 += 32; gB2 += 32;
    asm volatile("s_waitcnt vmcnt(0)" ::: "memory");
    __syncthreads();
    short8 af[4], bf[4];
#pragma unroll
    for (int mi = 0; mi < 4; ++mi) af[mi] = *(const short8*)&Alds[aoff[mi]];
#pragma unroll
    for (int ni = 0; ni < 4; ++ni) bf[ni] = *(const short8*)&Blds[boff[ni]];
#pragma unroll
    for (int mi = 0; mi < 4; ++mi)
#pragma unroll
      for (int ni = 0; ni < 4; ++ni)
        acc[mi][ni] = __builtin_amdgcn_mfma_f32_16x16x32_bf16(af[mi], bf[ni], acc[mi][ni], 0, 0, 0);
    __syncthreads();
  }

  if (MODE == 0) {
    unsigned short* C = (unsigned short*)outp;
#pragma unroll
    for (int mi = 0; mi < 4; ++mi) {
      int mb = m0 + wm + mi * 16 + g * 4;
#pragma unroll
      for (int ni = 0; ni < 4; ++ni) {
        int n = n0 + wn + ni * 16 + li;
#pragma unroll
        for (int r = 0; r < 4; ++r)
          C[(size_t)(mb + r) * N + n] = f2bf(acc[mi][ni][r]);
      }
    }
  } else if (MODE == 1) {
    unsigned short* C = (unsigned short*)outp;   // (B*1024) x 2048
#pragma unroll
    for (int mi = 0; mi < 4; ++mi) {
      int mb = m0 + wm + mi * 16 + g * 4;
      int bb = mb >> 11, s = mb & 2047;
#pragma unroll
      for (int ni = 0; ni < 4; ++ni) {
        int n = n0 + wn + ni * 16 + li;
        us4 pk = { f2bf(acc[mi][ni][0]), f2bf(acc[mi][ni][1]),
                   f2bf(acc[mi][ni][2]), f2bf(acc[mi][ni][3]) };
        *(us4*)&C[(size_t)(bb * 1024 + n) * 2048 + s] = pk;
      }
    }
  } else {
    float* C = (float*)outp;
#pragma unroll
    for (int mi = 0; mi < 4; ++mi) {
      int mb = m0 + wm + mi * 16 + g * 4;
#pragma unroll
      for (int ni = 0; ni < 4; ++ni) {
        int n = n0 + wn + ni * 16 + li;
#pragma unroll
        for (int r = 0; r < 4; ++r)
          C[(size_t)(mb + r) * N + n] = acc[mi][ni][r];
      }
    }
  }
}

// ---------------------------------------------------------------- attention v2
// Block = 512 threads (8 waves), owns q128-tile pair (p, 15-p) of one (b,h):
// uniform 34 k-iterations. Wave w handles 16 q rows. K/V tiles (64 keys)
// double-buffered in LDS via global_load_lds (XOR-swizzled source), counted
// vmcnt(2) so prefetch stays in flight across raw s_barriers.
__global__ __launch_bounds__(512, 4) void attn_kernel(const unsigned short* __restrict__ Qp,
                                                      const unsigned short* __restrict__ Kp,
                                                      const unsigned short* __restrict__ Vt,
                                                      const float* __restrict__ bias,
                                                      unsigned short* __restrict__ att) {
  __shared__ unsigned short Klds[2][64 * 64];
  __shared__ unsigned short Vlds[2][64 * 64];
  __shared__ unsigned short Plds[8][16 * 72];

  const int tid = threadIdx.x, lane = tid & 63, w = tid >> 6;
  const int g = lane >> 4, li = lane & 15;
  const int bh = blockIdx.y, b = bh >> 4, h = bh & 15;
  const int p = blockIdx.x;
  const int tA = p, tB = 15 - p;
  const int nA = 2 * tA + 2, nTot = nA + 2 * tB + 2;

  // staging source (lane-fixed): slot = tid; row = slot>>3, chunk swizzled by row&7
  const int srow = tid >> 3, swc = (tid & 7) ^ (srow & 7);
  const unsigned short* Ksrc0 = Kp + (size_t)(b * 2048 + srow) * 1024 + h * 64 + swc * 8;
  const unsigned short* Vsrc0 = Vt + (size_t)(b * 1024 + h * 64 + srow) * 2048 + swc * 8;

  // fragment read offsets (identical formula for K and V tiles)
  int foff[2][4];
#pragma unroll
  for (int ks = 0; ks < 2; ++ks)
#pragma unroll
    for (int i = 0; i < 4; ++i)
      foff[ks][i] = (i * 16 + li) * 64 + (((ks * 4 + g) ^ (li & 7)) * 8);

  unsigned short* Pl = &Plds[w][0];
  const float sc = 0.125f * 1.44269504088896340736f;    // scale * log2(e)

  short8 ones;
#pragma unroll
  for (int j = 0; j < 8; ++j) ones[j] = (short)0x3F80;  // bf16 1.0

  short8 qfr[2];
#pragma unroll
  for (int ks = 0; ks < 2; ++ks)
    qfr[ks] = *(const short8*)&Qp[((size_t)(b * 2048 + tA * 128 + w * 16 + li)) * 1024 +
                                  h * 64 + ks * 32 + g * 8];

  f32x4 acco[4] = {};
  f32x4 lacc = {};
  float mrow[4] = {-3.0e38f, -3.0e38f, -3.0e38f, -3.0e38f};

  // prologue: stage kt=0 into buf 0
  g2l16(Ksrc0, &Klds[0][w * 512]);
  g2l16(Vsrc0, &Vlds[0][w * 512]);

  int buf = 0;
#pragma unroll 1
  for (int it = 0; it < nTot; ++it) {
    const bool phaseA = it < nA;
    const int tile = phaseA ? tA : tB;
    const int kt = phaseA ? it : it - nA;
    const int qw = tile * 128 + w * 16;
    const bool active = (kt * 64 <= qw + 15);

    float bs[4];
    if (active) {
#pragma unroll
      for (int ni = 0; ni < 4; ++ni) bs[ni] = bias[b * 2048 + kt * 64 + ni * 16 + li];
    }

    const int itn = it + 1;
    if (itn < nTot) {
      const int ktn = itn < nA ? itn : itn - nA;
      g2l16(Ksrc0 + (size_t)ktn * 65536, &Klds[buf ^ 1][w * 512]);
      g2l16(Vsrc0 + (size_t)ktn * 64,    &Vlds[buf ^ 1][w * 512]);
    }
    asm volatile("s_waitcnt vmcnt(2)" ::: "memory");
    __builtin_amdgcn_s_barrier();

    if (active) {
      // ---- QK^T
      f32x4 s[4] = {};
#pragma unroll
      for (int ks = 0; ks < 2; ++ks) {
        short8 kf[4];
#pragma unroll
        for (int ni = 0; ni < 4; ++ni) kf[ni] = *(const short8*)&Klds[buf][foff[ks][ni]];
#pragma unroll
        for (int ni = 0; ni < 4; ++ni)
          s[ni] = __builtin_amdgcn_mfma_f32_16x16x32_bf16(qfr[ks], kf[ni], s[ni], 0, 0, 0);
      }
      // ---- scale + bias + causal (diagonal tiles only)
      const bool cz = (kt * 64 + 63 > qw);
      const int q0 = qw + g * 4;
#pragma unroll
      for (int ni = 0; ni < 4; ++ni) {
        const int key = kt * 64 + ni * 16 + li;
#pragma unroll
        for (int r = 0; r < 4; ++r) {
          float v = fmaf(s[ni][r], sc, bs[ni]);
          if (cz && key > q0 + r) v = -1.0e9f;
          s[ni][r] = v;
        }
      }
      // ---- row max over 16 key-lanes, rescale O and l
#pragma unroll
      for (int r = 0; r < 4; ++r) {
        float v = fmaxf(fmaxf(s[0][r], s[1][r]), fmaxf(s[2][r], s[3][r]));
        v = fmaxf(v, __shfl_xor(v, 1));
        v = fmaxf(v, __shfl_xor(v, 2));
        v = fmaxf(v, __shfl_xor(v, 4));
        v = fmaxf(v, __shfl_xor(v, 8));
        const float mn = fmaxf(mrow[r], v);
        const float al = exp2f(mrow[r] - mn);
        mrow[r] = mn;
        lacc[r] *= al;
#pragma unroll
        for (int df = 0; df < 4; ++df) acco[df][r] *= al;
      }
      // ---- p = exp2(s - m) -> bf16 -> LDS (16 rows, stride 72)
#pragma unroll
      for (int ni = 0; ni < 4; ++ni)
#pragma unroll
        for (int r = 0; r < 4; ++r)
          Pl[(g * 4 + r) * 72 + ni * 16 + li] = f2bf(exp2f(s[ni][r] - mrow[r]));
      // ---- PV (+ ones column for row-sum l)
#pragma unroll
      for (int ks = 0; ks < 2; ++ks) {
        const short8 pa = *(const short8*)&Pl[li * 72 + ks * 32 + g * 8];
        short8 vf[4];
#pragma unroll
        for (int df = 0; df < 4; ++df) vf[df] = *(const short8*)&Vlds[buf][foff[ks][df]];
#pragma unroll
        for (int df = 0; df < 4; ++df)
          acco[df] = __builtin_amdgcn_mfma_f32_16x16x32_bf16(pa, vf[df], acco[df], 0, 0, 0);
        lacc = __builtin_amdgcn_mfma_f32_16x16x32_bf16(pa, ones, lacc, 0, 0, 0);
      }
    }
    __builtin_amdgcn_s_barrier();
    buf ^= 1;

    if (it == nA - 1 || it == nTot - 1) {
      // epilogue for finished tile
      const int qb0 = tile * 128 + w * 16 + g * 4;
#pragma unroll
      for (int df = 0; df < 4; ++df) {
        const int d = h * 64 + df * 16 + li;
#pragma unroll
        for (int r = 0; r < 4; ++r)
          att[(size_t)(b * 2048 + qb0 + r) * 1024 + d] = f2bf(acco[df][r] / lacc[r]);
      }
      if (it == nA - 1) {
#pragma unroll
        for (int df = 0; df < 4; ++df) acco[df] = (f32x4){0.f, 0.f, 0.f, 0.f};
        lacc = (f32x4){0.f, 0.f, 0.f, 0.f};
#pragma unroll
        for (int r = 0; r < 4; ++r) mrow[r] = -3.0e38f;
#pragma unroll
        for (int ks = 0; ks < 2; ++ks)
          qfr[ks] = *(const short8*)&Qp[((size_t)(b * 2048 + tB * 128 + w * 16 + li)) * 1024 +
                                        h * 64 + ks * 32 + g * 8];
      }
    }
  }
}

// ---------------------------------------------------------------- launch
extern "C" void kernel_launch(void* const* d_in, const int* in_sizes, int n_in,
                              void* d_out, int out_size, void* d_ws, size_t ws_size,
                              hipStream_t stream) {
  const float* q_raw  = (const float*)d_in[0];
  const float* kv_raw = (const float*)d_in[1];
  const int*   pmask  = (const int*)d_in[2];
  const float* Wq = (const float*)d_in[3];
  const float* Wk = (const float*)d_in[4];
  const float* Wv = (const float*)d_in[5];
  const float* Wo = (const float*)d_in[6];
  float* out = (float*)d_out;

  const size_t NEL = 8388608;   // B*S*D
  const size_t WEL = 1048576;   // D*D
  unsigned short* ws   = (unsigned short*)d_ws;
  unsigned short* qbf  = ws;              // reused as att after projections
  unsigned short* kvbf = qbf + NEL;
  unsigned short* wbf  = kvbf + NEL;      // Wq,Wk,Wv,Wo bf16 back-to-back
  unsigned short* Qp   = wbf + 4 * WEL;
  unsigned short* Kp   = Qp + NEL;
  unsigned short* Vtp  = Kp + NEL;        // (B,H,DH,S) transposed V
  float*          bias = (float*)(Vtp + NEL);
  unsigned short* att  = qbf;             // alias (qbf dead after projections)

  cvt_kernel<<<2048, 256, 0, stream>>>(q_raw,  qbf,  (int)(NEL / 4));
  cvt_kernel<<<2048, 256, 0, stream>>>(kv_raw, kvbf, (int)(NEL / 4));
  cvt_kernel<<<256, 256, 0, stream>>>(Wq, wbf,           (int)(WEL / 4));
  cvt_kernel<<<256, 256, 0, stream>>>(Wk, wbf + WEL,     (int)(WEL / 4));
  cvt_kernel<<<256, 256, 0, stream>>>(Wv, wbf + 2 * WEL, (int)(WEL / 4));
  cvt_kernel<<<256, 256, 0, stream>>>(Wo, wbf + 3 * WEL, (int)(WEL / 4));
  bias_kernel<<<32, 256, 0, stream>>>(pmask, bias, 8192);

  dim3 gg(8, 64);  // N/128, M/128
  gemm_nt<0><<<gg, 256, 0, stream>>>(qbf,  wbf,           (void*)Qp,  8192, 1024, 1024);
  gemm_nt<0><<<gg, 256, 0, stream>>>(kvbf, wbf + WEL,     (void*)Kp,  8192, 1024, 1024);
  gemm_nt<1><<<gg, 256, 0, stream>>>(kvbf, wbf + 2 * WEL, (void*)Vtp, 8192, 1024, 1024);

  attn_kernel<<<dim3(8, 64), 512, 0, stream>>>(Qp, Kp, Vtp, bias, att);

  gemm_nt<2><<<gg, 256, 0, stream>>>(att, wbf + 3 * WEL, (void*)out, 8192, 1024, 1024);
}